// Round 1
// baseline (865.114 us; speedup 1.0000x reference)
//
#include <hip/hip_runtime.h>
#include <stdint.h>

#define BM 128
#define BN 128
#define BK 32
#define DIMD 512
#define NROWS 65536
#define QOFF 1
#define PERPOFF 33554433
#define PROBSOFF 33554434
#define NELEM 33554432

typedef __attribute__((ext_vector_type(8))) short bf16x8;
typedef __attribute__((ext_vector_type(4))) short s16x4;
typedef __attribute__((ext_vector_type(4))) float f32x4;

typedef const __attribute__((address_space(1))) void* gas_ptr;
typedef __attribute__((address_space(3))) void* las_ptr;

__device__ __forceinline__ short f2bf(float x){
  uint32_t u = __builtin_bit_cast(uint32_t, x);
  uint32_t r = (u + 0x7fffu + ((u >> 16) & 1u)) >> 16;
  return (short)(uint16_t)r;
}
__device__ __forceinline__ float bf2f(short h){
  return __builtin_bit_cast(float, ((uint32_t)(uint16_t)h) << 16);
}

// async stage of a 128x32 bf16 tile (row-major, leading dim ld) into LDS (128*32 shorts)
__device__ __forceinline__ void stage_bf16(const short* __restrict__ g, int row0, int ld, int k0,
                                           short* lds){
  int tid = threadIdx.x;
#pragma unroll
  for (int i = 0; i < 2; ++i){
    int t = tid + i * 256;
    int row = t >> 2, c = t & 3;
    const short* src = g + (long)(row0 + row) * ld + k0 + c * 8;
    __builtin_amdgcn_global_load_lds((gas_ptr)src, (las_ptr)(lds + t * 8), 16, 0, 0);
  }
}

// stage a 128x32 fp32 tile, splitting into hi/lo bf16 LDS tiles
__device__ __forceinline__ void stage_f32_split(const float* __restrict__ g, int row0, int ld, int k0,
                                                short* hi, short* lo){
  int tid = threadIdx.x;
#pragma unroll
  for (int i = 0; i < 4; ++i){
    int t = tid + i * 256;               // 0..1023 -> 128 rows x 8 float4
    int row = t >> 3, c = t & 7;
    const float4 v = *(const float4*)(g + (long)(row0 + row) * ld + k0 + c * 4);
    short h0 = f2bf(v.x), h1 = f2bf(v.y), h2 = f2bf(v.z), h3 = f2bf(v.w);
    s16x4 hv; hv[0] = h0; hv[1] = h1; hv[2] = h2; hv[3] = h3;
    s16x4 lv;
    lv[0] = f2bf(v.x - bf2f(h0)); lv[1] = f2bf(v.y - bf2f(h1));
    lv[2] = f2bf(v.z - bf2f(h2)); lv[3] = f2bf(v.w - bf2f(h3));
    *(s16x4*)(hi + row * BK + c * 4) = hv;
    *(s16x4*)(lo + row * BK + c * 4) = lv;
  }
}

__device__ __forceinline__ bf16x8 frag(const short* lds, int r, int q){
  return *(const bf16x8*)(lds + r * BK + q * 8);
}

// ---------------- weight conversion ----------------
// block b handles input-dim row b of mean_W/logvar_W and codebook row b of embedding
__global__ __launch_bounds__(256) void k_convert_w(
    const float* __restrict__ meanW, const float* __restrict__ lvW, const float* __restrict__ emb,
    short* __restrict__ MWThi, short* __restrict__ MWTlo,
    short* __restrict__ VWThi, short* __restrict__ VWTlo,
    short* __restrict__ E, short* __restrict__ ET, float* __restrict__ enorm)
{
  int b = blockIdx.x;
  int tid = threadIdx.x;
  float esum = 0.f;
  for (int j = tid; j < 512; j += 256){
    float w = meanW[b * 512 + j];
    short h = f2bf(w); short l = f2bf(w - bf2f(h));
    MWThi[j * 512 + b] = h; MWTlo[j * 512 + b] = l;
    float v = lvW[b * 512 + j];
    h = f2bf(v); l = f2bf(v - bf2f(h));
    VWThi[j * 512 + b] = h; VWTlo[j * 512 + b] = l;
    float e = emb[b * 512 + j];
    short eh = f2bf(e);
    E[b * 512 + j] = eh;       // [k][d]  (B^T layout for x@e^T)
    ET[j * 512 + b] = eh;      // [d][k]  (B^T layout for probs@e)
    esum += e * e;
  }
  for (int o = 32; o >= 1; o >>= 1) esum += __shfl_xor(esum, o);
  __shared__ float red[4];
  if ((tid & 63) == 0) red[tid >> 6] = esum;
  __syncthreads();
  if (tid == 0) enorm[b] = red[0] + red[1] + red[2] + red[3];
}

// ---------------- G1: x = inputs @ mean_W + mean_b (split bf16, fp32-accurate) ----------------
__global__ __launch_bounds__(256, 2) void k_gemm_mean(
    const float* __restrict__ inp, const short* __restrict__ Bhi, const short* __restrict__ Blo,
    const float* __restrict__ bias, short* __restrict__ Xhi, short* __restrict__ Xlo,
    float* __restrict__ xnorm)
{
  __shared__ short Ah[BM * BK], Al[BM * BK], Bh[BN * BK], Bl[BN * BK];
  int tid = threadIdx.x;
  int n0 = blockIdx.x * BM, c0 = blockIdx.y * BN;
  int lane = tid & 63, wid = tid >> 6;
  int wm = wid >> 1, wn = wid & 1;
  int q = lane >> 4, m = lane & 15;
  f32x4 acc[4][4];
#pragma unroll
  for (int i = 0; i < 4; i++)
#pragma unroll
    for (int j = 0; j < 4; j++)
#pragma unroll
      for (int r = 0; r < 4; r++) acc[i][j][r] = 0.f;

  for (int k0 = 0; k0 < DIMD; k0 += BK){
    __syncthreads();
    stage_f32_split(inp, n0, DIMD, k0, Ah, Al);
    stage_bf16(Bhi, c0, DIMD, k0, Bh);
    stage_bf16(Blo, c0, DIMD, k0, Bl);
    __syncthreads();
    bf16x8 ah[4], al[4], bh[4], bl[4];
#pragma unroll
    for (int i = 0; i < 4; i++){
      ah[i] = frag(Ah, wm * 64 + i * 16 + m, q);
      al[i] = frag(Al, wm * 64 + i * 16 + m, q);
      bh[i] = frag(Bh, wn * 64 + i * 16 + m, q);
      bl[i] = frag(Bl, wn * 64 + i * 16 + m, q);
    }
#pragma unroll
    for (int i = 0; i < 4; i++)
#pragma unroll
      for (int j = 0; j < 4; j++){
        acc[i][j] = __builtin_amdgcn_mfma_f32_16x16x32_bf16(ah[i], bh[j], acc[i][j], 0, 0, 0);
        acc[i][j] = __builtin_amdgcn_mfma_f32_16x16x32_bf16(ah[i], bl[j], acc[i][j], 0, 0, 0);
        acc[i][j] = __builtin_amdgcn_mfma_f32_16x16x32_bf16(al[i], bh[j], acc[i][j], 0, 0, 0);
      }
  }
#pragma unroll
  for (int i = 0; i < 4; i++){
#pragma unroll
    for (int r = 0; r < 4; r++){
      int row = n0 + wm * 64 + i * 16 + q * 4 + r;
      float xn = 0.f;
#pragma unroll
      for (int j = 0; j < 4; j++){
        int col = c0 + wn * 64 + j * 16 + m;
        float x = acc[i][j][r] + bias[col];
        short h = f2bf(x);
        short l = f2bf(x - bf2f(h));
        Xhi[(long)row * DIMD + col] = h;
        Xlo[(long)row * DIMD + col] = l;
        xn += x * x;
      }
      xn += __shfl_xor(xn, 1); xn += __shfl_xor(xn, 2);
      xn += __shfl_xor(xn, 4); xn += __shfl_xor(xn, 8);
      if (m == 0) atomicAdd(&xnorm[row], xn);   // 8 partials/row (4 y-blocks x 2 wn-waves)
    }
  }
}

// ---------------- G2a: z_logvar = x @ logvar_W + logvar_b (split bf16) ----------------
__global__ __launch_bounds__(256, 2) void k_gemm_logvar(
    const short* __restrict__ Xh, const short* __restrict__ Xl,
    const short* __restrict__ Bhi, const short* __restrict__ Blo,
    const float* __restrict__ bias, float* __restrict__ zlv)
{
  __shared__ short Ah[BM * BK], Al[BM * BK], Bh[BN * BK], Bl[BN * BK];
  int tid = threadIdx.x;
  int n0 = blockIdx.x * BM, c0 = blockIdx.y * BN;
  int lane = tid & 63, wid = tid >> 6;
  int wm = wid >> 1, wn = wid & 1;
  int q = lane >> 4, m = lane & 15;
  f32x4 acc[4][4];
#pragma unroll
  for (int i = 0; i < 4; i++)
#pragma unroll
    for (int j = 0; j < 4; j++)
#pragma unroll
      for (int r = 0; r < 4; r++) acc[i][j][r] = 0.f;

  for (int k0 = 0; k0 < DIMD; k0 += BK){
    __syncthreads();
    stage_bf16(Xh, n0, DIMD, k0, Ah);
    stage_bf16(Xl, n0, DIMD, k0, Al);
    stage_bf16(Bhi, c0, DIMD, k0, Bh);
    stage_bf16(Blo, c0, DIMD, k0, Bl);
    __syncthreads();
    bf16x8 ah[4], al[4], bh[4], bl[4];
#pragma unroll
    for (int i = 0; i < 4; i++){
      ah[i] = frag(Ah, wm * 64 + i * 16 + m, q);
      al[i] = frag(Al, wm * 64 + i * 16 + m, q);
      bh[i] = frag(Bh, wn * 64 + i * 16 + m, q);
      bl[i] = frag(Bl, wn * 64 + i * 16 + m, q);
    }
#pragma unroll
    for (int i = 0; i < 4; i++)
#pragma unroll
      for (int j = 0; j < 4; j++){
        acc[i][j] = __builtin_amdgcn_mfma_f32_16x16x32_bf16(ah[i], bh[j], acc[i][j], 0, 0, 0);
        acc[i][j] = __builtin_amdgcn_mfma_f32_16x16x32_bf16(ah[i], bl[j], acc[i][j], 0, 0, 0);
        acc[i][j] = __builtin_amdgcn_mfma_f32_16x16x32_bf16(al[i], bh[j], acc[i][j], 0, 0, 0);
      }
  }
#pragma unroll
  for (int i = 0; i < 4; i++)
#pragma unroll
    for (int r = 0; r < 4; r++){
      int row = n0 + wm * 64 + i * 16 + q * 4 + r;
#pragma unroll
      for (int j = 0; j < 4; j++){
        int col = c0 + wn * 64 + j * 16 + m;
        zlv[(long)row * DIMD + col] = acc[i][j][r] + bias[col];
      }
    }
}

// ---------------- G2b: S = x_hi @ e^T (plain bf16) ----------------
__global__ __launch_bounds__(256, 2) void k_gemm_dist(
    const short* __restrict__ Xh, const short* __restrict__ E, float* __restrict__ S)
{
  __shared__ short Ah[BM * BK], Bh[BN * BK];
  int tid = threadIdx.x;
  int n0 = blockIdx.x * BM, c0 = blockIdx.y * BN;
  int lane = tid & 63, wid = tid >> 6;
  int wm = wid >> 1, wn = wid & 1;
  int q = lane >> 4, m = lane & 15;
  f32x4 acc[4][4];
#pragma unroll
  for (int i = 0; i < 4; i++)
#pragma unroll
    for (int j = 0; j < 4; j++)
#pragma unroll
      for (int r = 0; r < 4; r++) acc[i][j][r] = 0.f;

  for (int k0 = 0; k0 < DIMD; k0 += BK){
    __syncthreads();
    stage_bf16(Xh, n0, DIMD, k0, Ah);
    stage_bf16(E, c0, DIMD, k0, Bh);
    __syncthreads();
    bf16x8 a[4], b[4];
#pragma unroll
    for (int i = 0; i < 4; i++){
      a[i] = frag(Ah, wm * 64 + i * 16 + m, q);
      b[i] = frag(Bh, wn * 64 + i * 16 + m, q);
    }
#pragma unroll
    for (int i = 0; i < 4; i++)
#pragma unroll
      for (int j = 0; j < 4; j++)
        acc[i][j] = __builtin_amdgcn_mfma_f32_16x16x32_bf16(a[i], b[j], acc[i][j], 0, 0, 0);
  }
#pragma unroll
  for (int i = 0; i < 4; i++)
#pragma unroll
    for (int r = 0; r < 4; r++){
      int row = n0 + wm * 64 + i * 16 + q * 4 + r;
#pragma unroll
      for (int j = 0; j < 4; j++){
        int col = c0 + wn * 64 + j * 16 + m;
        S[(long)row * DIMD + col] = acc[i][j][r];
      }
    }
}

// ---------------- G3: fused softmax over K=512 ----------------
// NOTE: probs_out may alias S (in-place): each element is read before it is written by the same thread.
__global__ __launch_bounds__(256) void k_softmax(
    const float* __restrict__ zlv, const float* Sm, const float* __restrict__ xnorm,
    const float* __restrict__ enorm, float* probs_out, short* __restrict__ probs_bf,
    float* __restrict__ Pacc)
{
  __shared__ float red[4];
  int tid = threadIdx.x;
  int n0 = blockIdx.x * 32;
  int k1 = tid, k2 = tid + 256;
  float en1 = enorm[k1], en2 = enorm[k2];
  float pa1 = 0.f, pa2 = 0.f;
  const float inv400 = 1.0f / 400.0f;
  for (int r = 0; r < 32; ++r){
    long n = n0 + r;
    float xn = xnorm[n];
    float z1 = zlv[n * 512 + k1], z2 = zlv[n * 512 + k2];
    float s1 = Sm[n * 512 + k1],  s2 = Sm[n * 512 + k2];
    float sm1 = __expf(-2.f * z1), sm2 = __expf(-2.f * z2);
    float L1 = z1 - 0.5f * inv400 * (xn + en1 - 2.f * s1) * sm1;
    float L2 = z2 - 0.5f * inv400 * (xn + en2 - 2.f * s2) * sm2;
    float mx = fmaxf(L1, L2);
    for (int o = 32; o >= 1; o >>= 1) mx = fmaxf(mx, __shfl_xor(mx, o));
    if ((tid & 63) == 0) red[tid >> 6] = mx;
    __syncthreads();
    mx = fmaxf(fmaxf(red[0], red[1]), fmaxf(red[2], red[3]));
    __syncthreads();
    float p1 = __expf(L1 - mx), p2 = __expf(L2 - mx);
    float sm = p1 + p2;
    for (int o = 32; o >= 1; o >>= 1) sm += __shfl_xor(sm, o);
    if ((tid & 63) == 0) red[tid >> 6] = sm;
    __syncthreads();
    sm = red[0] + red[1] + red[2] + red[3];
    __syncthreads();
    float inv = 1.0f / sm;
    float q1 = p1 * inv, q2 = p2 * inv;
    probs_out[n * 512 + k1] = q1;
    probs_out[n * 512 + k2] = q2;
    probs_bf[n * 512 + k1] = f2bf(q1);
    probs_bf[n * 512 + k2] = f2bf(q2);
    pa1 += q1; pa2 += q2;
  }
  atomicAdd(&Pacc[k1], pa1);
  atomicAdd(&Pacc[k2], pa2);
}

// ---------------- G4: quantized = probs @ embedding (plain bf16) + loss reduction ----------------
__global__ __launch_bounds__(256, 2) void k_gemm_quant(
    const short* __restrict__ P, const short* __restrict__ ET,
    const float* __restrict__ inp, float* __restrict__ qout, float* __restrict__ lossacc)
{
  __shared__ short Ah[BM * BK], Bh[BN * BK];
  __shared__ float red[4];
  int tid = threadIdx.x;
  int n0 = blockIdx.x * BM, c0 = blockIdx.y * BN;
  int lane = tid & 63, wid = tid >> 6;
  int wm = wid >> 1, wn = wid & 1;
  int q = lane >> 4, m = lane & 15;
  f32x4 acc[4][4];
#pragma unroll
  for (int i = 0; i < 4; i++)
#pragma unroll
    for (int j = 0; j < 4; j++)
#pragma unroll
      for (int r = 0; r < 4; r++) acc[i][j][r] = 0.f;

  for (int k0 = 0; k0 < DIMD; k0 += BK){
    __syncthreads();
    stage_bf16(P, n0, DIMD, k0, Ah);
    stage_bf16(ET, c0, DIMD, k0, Bh);
    __syncthreads();
    bf16x8 a[4], b[4];
#pragma unroll
    for (int i = 0; i < 4; i++){
      a[i] = frag(Ah, wm * 64 + i * 16 + m, q);
      b[i] = frag(Bh, wn * 64 + i * 16 + m, q);
    }
#pragma unroll
    for (int i = 0; i < 4; i++)
#pragma unroll
      for (int j = 0; j < 4; j++)
        acc[i][j] = __builtin_amdgcn_mfma_f32_16x16x32_bf16(a[i], b[j], acc[i][j], 0, 0, 0);
  }
  float lsum = 0.f;
#pragma unroll
  for (int i = 0; i < 4; i++)
#pragma unroll
    for (int r = 0; r < 4; r++){
      int row = n0 + wm * 64 + i * 16 + q * 4 + r;
#pragma unroll
      for (int j = 0; j < 4; j++){
        int col = c0 + wn * 64 + j * 16 + m;
        float qv = acc[i][j][r];
        qout[(long)row * DIMD + col] = qv;
        float d = qv - inp[(long)row * DIMD + col];
        lsum += d * d;
      }
    }
  for (int o = 32; o >= 1; o >>= 1) lsum += __shfl_xor(lsum, o);
  if (lane == 0) red[wid] = lsum;
  __syncthreads();
  if (tid == 0) atomicAdd(lossacc, red[0] + red[1] + red[2] + red[3]);
}

// ---------------- G5: loss + perplexity ----------------
__global__ __launch_bounds__(256) void k_final(
    const float* __restrict__ Pacc, const float* __restrict__ lossacc, float* __restrict__ out)
{
  int tid = threadIdx.x;
  float h = 0.f;
  for (int k = tid; k < 512; k += 256){
    float a = Pacc[k] * (1.0f / 65536.0f);
    h += a * __logf(a + 1e-10f);
  }
  for (int o = 32; o >= 1; o >>= 1) h += __shfl_xor(h, o);
  __shared__ float red[4];
  if ((tid & 63) == 0) red[tid >> 6] = h;
  __syncthreads();
  if (tid == 0){
    float H = red[0] + red[1] + red[2] + red[3];
    out[0] = 1.25f * lossacc[0] * (1.0f / (float)NELEM);
    out[PERPOFF] = __expf(-H);
  }
}

extern "C" void kernel_launch(void* const* d_in, const int* in_sizes, int n_in,
                              void* d_out, int out_size, void* d_ws, size_t ws_size,
                              hipStream_t stream)
{
  const float* inp   = (const float*)d_in[0];
  const float* meanW = (const float*)d_in[1];
  const float* meanb = (const float*)d_in[2];
  const float* lvW   = (const float*)d_in[3];
  const float* lvb   = (const float*)d_in[4];
  const float* emb   = (const float*)d_in[5];
  float* out = (float*)d_out;

  // workspace carve (~138 MB)
  char* w = (char*)d_ws;
  short* Xhi = (short*)w;   w += (size_t)NROWS * DIMD * 2;      // 67.1 MB
  short* Xlo = (short*)w;   w += (size_t)NROWS * DIMD * 2;      // 67.1 MB (reused as probs_bf16)
  short* MWThi = (short*)w; w += 512 * 512 * 2;
  short* MWTlo = (short*)w; w += 512 * 512 * 2;
  short* VWThi = (short*)w; w += 512 * 512 * 2;
  short* VWTlo = (short*)w; w += 512 * 512 * 2;
  short* E     = (short*)w; w += 512 * 512 * 2;
  short* ET    = (short*)w; w += 512 * 512 * 2;
  float* enorm = (float*)w; w += 512 * 4;
  float* stats = (float*)w;                    // xnorm[65536] + Pacc[512] + lossacc
  float* xnorm   = stats;
  float* Pacc    = stats + NROWS;
  float* lossacc = stats + NROWS + 512;

  // d_out reuse as scratch: z_logvar lives in the quantized slot, S lives in the probs slot
  float* zlv = out + QOFF;       // [N,512] fp32, overwritten later by quantized
  float* S   = out + PROBSOFF;   // [N,512] fp32, overwritten in-place by probs

  hipMemsetAsync(stats, 0, (size_t)(NROWS + 512 + 16) * 4, stream);

  k_convert_w<<<512, 256, 0, stream>>>(meanW, lvW, emb, MWThi, MWTlo, VWThi, VWTlo, E, ET, enorm);
  k_gemm_mean<<<dim3(512, 4), 256, 0, stream>>>(inp, MWThi, MWTlo, meanb, Xhi, Xlo, xnorm);
  k_gemm_logvar<<<dim3(512, 4), 256, 0, stream>>>(Xhi, Xlo, VWThi, VWTlo, lvb, zlv);
  k_gemm_dist<<<dim3(512, 4), 256, 0, stream>>>(Xhi, E, S);
  k_softmax<<<2048, 256, 0, stream>>>(zlv, S, xnorm, enorm, out + PROBSOFF, Xlo, Pacc);
  k_gemm_quant<<<dim3(512, 4), 256, 0, stream>>>(Xlo, ET, inp, out + QOFF, lossacc);
  k_final<<<1, 256, 0, stream>>>(Pacc, lossacc, out);
}